// Round 6
// baseline (424.263 us; speedup 1.0000x reference)
//
#include <hip/hip_runtime.h>
#include <math.h>

#define BATCH 1024
#define FIN   256
#define HDIM  512
#define PDIM  128

typedef unsigned short u16;
typedef __attribute__((ext_vector_type(8))) short short8;
typedef __attribute__((ext_vector_type(4))) float fx4;

#define LOG2E 1.4426950408889634f

__device__ __forceinline__ float b2f(u16 b) {
    return __uint_as_float(((unsigned)b) << 16);
}
__device__ __forceinline__ u16 f2b(float f) {
    unsigned u = __float_as_uint(f);
    u += 0x7fffu + ((u >> 16) & 1u);   // RNE
    return (u16)(u >> 16);
}

#if defined(__has_builtin)
#if __has_builtin(__builtin_amdgcn_exp2f)
#define EXP2(x) __builtin_amdgcn_exp2f(x)
#endif
#endif
#ifndef EXP2
#define EXP2(x) __expf(0.69314718055994531f * (x))
#endif

__device__ __forceinline__ float2 pk_fma(float2 a, float2 b, float2 c) {
    float2 d;
    asm("v_pk_fma_f32 %0, %1, %2, %3" : "=v"(d) : "v"(a), "v"(b), "v"(c));
    return d;
}
__device__ __forceinline__ float2 pk_add(float2 a, float2 b) {
    float2 d;
    asm("v_pk_add_f32 %0, %1, %2" : "=v"(d) : "v"(a), "v"(b));
    return d;
}

// B-fragment (MFMA 16x16x32 bf16) loaded straight from fp32 row-major W[N,K],
// converted in-register. row = n index, 8 consecutive k's.
__device__ __forceinline__ short8 ldBf32(const float* __restrict__ W, int row, int K, int k0) {
    const float4 f0 = *(const float4*)&W[(size_t)row * K + k0];
    const float4 f1 = *(const float4*)&W[(size_t)row * K + k0 + 4];
    short8 s;
    s[0] = (short)f2b(f0.x); s[1] = (short)f2b(f0.y);
    s[2] = (short)f2b(f0.z); s[3] = (short)f2b(f0.w);
    s[4] = (short)f2b(f1.x); s[5] = (short)f2b(f1.y);
    s[6] = (short)f2b(f1.z); s[7] = (short)f2b(f1.w);
    return s;
}

#define MFMA(a, b, c) __builtin_amdgcn_mfma_f32_16x16x32_bf16(a, b, c, 0, 0, 0)

#define LSTR 520   // LDS row stride (bf16 elems): 512 + 8 pad
#define XSTR 264   // x-tile stride: 256 + 8 pad

// ============ fused1: h = lin0(x); q/k/v = h @ w{q,k,v}^T + b ===============
// 64 blocks x 512 thr; block handles 16 batch rows end-to-end.
__global__ __launch_bounds__(512, 2) void fused1(
    const float* __restrict__ x, const float* __restrict__ wl0, const float* __restrict__ bl0,
    const float* __restrict__ wq, const float* __restrict__ bq,
    const float* __restrict__ wk, const float* __restrict__ bk,
    const float* __restrict__ wv, const float* __restrict__ bv,
    u16* __restrict__ hA, u16* __restrict__ qb, u16* __restrict__ kb, u16* __restrict__ vb)
{
    __shared__ __align__(16) u16 xs[16 * XSTR];
    __shared__ __align__(16) u16 hs[16 * LSTR];

    const int tid = threadIdx.x;
    const int lane = tid & 63, wave = tid >> 6;   // 8 waves
    const int quad = lane >> 4, l16 = lane & 15;
    const int bm = blockIdx.x * 16;

    // ---- stage X: x rows -> LDS bf16 ----
    {
        const int row = tid >> 5;            // 16 rows, 32 thr each
        const int col = (tid & 31) * 8;
        const float4 f0 = *(const float4*)&x[(size_t)(bm + row) * FIN + col];
        const float4 f1 = *(const float4*)&x[(size_t)(bm + row) * FIN + col + 4];
        short8 s;
        s[0] = (short)f2b(f0.x); s[1] = (short)f2b(f0.y);
        s[2] = (short)f2b(f0.z); s[3] = (short)f2b(f0.w);
        s[4] = (short)f2b(f1.x); s[5] = (short)f2b(f1.y);
        s[6] = (short)f2b(f1.z); s[7] = (short)f2b(f1.w);
        *(short8*)&xs[row * XSTR + col] = s;
    }
    __syncthreads();

    // ---- stage H: h[16,512] = x @ wl0^T + bl0 ; wave w -> cols w*64.. ----
    {
        const int bn = wave * 64;
        fx4 acc[4] = {};
        for (int kt = 0; kt < FIN; kt += 32) {
            const short8 a = *(const short8*)&xs[l16 * XSTR + kt + quad * 8];
#pragma unroll
            for (int j = 0; j < 4; j++) {
                const short8 b = ldBf32(wl0, bn + j * 16 + l16, FIN, kt + quad * 8);
                acc[j] = MFMA(a, b, acc[j]);
            }
        }
#pragma unroll
        for (int j = 0; j < 4; j++) {
            const int n_ = bn + j * 16 + l16;
            const float bv_ = bl0[n_];
#pragma unroll
            for (int r = 0; r < 4; r++) {
                const int m_ = quad * 4 + r;
                const u16 hb = f2b(acc[j][r] + bv_);
                hs[m_ * LSTR + n_] = hb;
                hA[(size_t)(bm + m_) * HDIM + n_] = hb;
            }
        }
    }
    __syncthreads();

    // ---- stage QKV: q/k/v = h @ w^T + b ----
    {
        const int bn = wave * 64;
        const float* Wm[3] = {wq, wk, wv};
        const float* Bm[3] = {bq, bk, bv};
        u16* Om[3] = {qb, kb, vb};
#pragma unroll
        for (int s = 0; s < 3; s++) {
            const float* W = Wm[s];
            fx4 acc[4] = {};
            for (int kt = 0; kt < HDIM; kt += 32) {
                const short8 a = *(const short8*)&hs[l16 * LSTR + kt + quad * 8];
#pragma unroll
                for (int j = 0; j < 4; j++) {
                    const short8 b = ldBf32(W, bn + j * 16 + l16, HDIM, kt + quad * 8);
                    acc[j] = MFMA(a, b, acc[j]);
                }
            }
            u16* O = Om[s];
            const float* Bi = Bm[s];
#pragma unroll
            for (int j = 0; j < 4; j++) {
                const int n_ = bn + j * 16 + l16;
                const float bv_ = Bi[n_];
#pragma unroll
                for (int r = 0; r < 4; r++) {
                    const int m_ = quad * 4 + r;
                    O[(size_t)(bm + m_) * HDIM + n_] = f2b(acc[j][r] + bv_);
                }
            }
        }
    }
}

// ====== fused2: hA2 = hB + gelu(fc1(hB)); q/k/v = hA2 @ w2^T + b ============
__global__ __launch_bounds__(512, 2) void fused2(
    const u16* __restrict__ hB,
    const float* __restrict__ wf, const float* __restrict__ bf,
    const float* __restrict__ wq, const float* __restrict__ bq,
    const float* __restrict__ wk, const float* __restrict__ bk,
    const float* __restrict__ wv, const float* __restrict__ bv,
    u16* __restrict__ hA, u16* __restrict__ qb, u16* __restrict__ kb, u16* __restrict__ vb)
{
    __shared__ __align__(16) u16 hs[16 * LSTR];    // hB
    __shared__ __align__(16) u16 hs2[16 * LSTR];   // hA2

    const int tid = threadIdx.x;
    const int lane = tid & 63, wave = tid >> 6;
    const int quad = lane >> 4, l16 = lane & 15;
    const int bm = blockIdx.x * 16;

    // ---- load hB rows -> LDS ----
    {
        const int row = tid >> 5;
        const int col = (tid & 31) * 16;
        *(short8*)&hs[row * LSTR + col]     = *(const short8*)&hB[(size_t)(bm + row) * HDIM + col];
        *(short8*)&hs[row * LSTR + col + 8] = *(const short8*)&hB[(size_t)(bm + row) * HDIM + col + 8];
    }
    __syncthreads();

    // ---- fc1 + gelu + residual -> hs2 (LDS) + hA (global) ----
    {
        const int bn = wave * 64;
        fx4 acc[4] = {};
        for (int kt = 0; kt < HDIM; kt += 32) {
            const short8 a = *(const short8*)&hs[l16 * LSTR + kt + quad * 8];
#pragma unroll
            for (int j = 0; j < 4; j++) {
                const short8 b = ldBf32(wf, bn + j * 16 + l16, HDIM, kt + quad * 8);
                acc[j] = MFMA(a, b, acc[j]);
            }
        }
#pragma unroll
        for (int j = 0; j < 4; j++) {
            const int n_ = bn + j * 16 + l16;
            const float bv_ = bf[n_];
#pragma unroll
            for (int r = 0; r < 4; r++) {
                const int m_ = quad * 4 + r;
                const float t = acc[j][r] + bv_;
                const float g = 0.5f * t * (1.0f + erff(t * 0.70710678118654752f));
                const u16 hb = f2b(b2f(hs[m_ * LSTR + n_]) + g);
                hs2[m_ * LSTR + n_] = hb;
                hA[(size_t)(bm + m_) * HDIM + n_] = hb;
            }
        }
    }
    __syncthreads();

    // ---- qkv from hs2 ----
    {
        const int bn = wave * 64;
        const float* Wm[3] = {wq, wk, wv};
        const float* Bm[3] = {bq, bk, bv};
        u16* Om[3] = {qb, kb, vb};
#pragma unroll
        for (int s = 0; s < 3; s++) {
            const float* W = Wm[s];
            fx4 acc[4] = {};
            for (int kt = 0; kt < HDIM; kt += 32) {
                const short8 a = *(const short8*)&hs2[l16 * LSTR + kt + quad * 8];
#pragma unroll
                for (int j = 0; j < 4; j++) {
                    const short8 b = ldBf32(W, bn + j * 16 + l16, HDIM, kt + quad * 8);
                    acc[j] = MFMA(a, b, acc[j]);
                }
            }
            u16* O = Om[s];
            const float* Bi = Bm[s];
#pragma unroll
            for (int j = 0; j < 4; j++) {
                const int n_ = bn + j * 16 + l16;
                const float bv_ = Bi[n_];
#pragma unroll
                for (int r = 0; r < 4; r++) {
                    const int m_ = quad * 4 + r;
                    O[(size_t)(bm + m_) * HDIM + n_] = f2b(acc[j][r] + bv_);
                }
            }
        }
    }
}

// ====== fused3: hA3 = hB + gelu(fc1(hB)); fea = hA3 @ wfe^T + fb; head ======
__global__ __launch_bounds__(512, 2) void fused3(
    const u16* __restrict__ hB,
    const float* __restrict__ wf, const float* __restrict__ bf,
    const float* __restrict__ wfe, const float* __restrict__ feb,
    const float* __restrict__ rw, const float* __restrict__ rb,
    float* __restrict__ fea, float* __restrict__ out)
{
    __shared__ __align__(16) u16 hs[16 * LSTR];
    __shared__ __align__(16) u16 hs2[16 * LSTR];
    __shared__ float part[8][16];

    const int tid = threadIdx.x;
    const int lane = tid & 63, wave = tid >> 6;
    const int quad = lane >> 4, l16 = lane & 15;
    const int bm = blockIdx.x * 16;

    {
        const int row = tid >> 5;
        const int col = (tid & 31) * 16;
        *(short8*)&hs[row * LSTR + col]     = *(const short8*)&hB[(size_t)(bm + row) * HDIM + col];
        *(short8*)&hs[row * LSTR + col + 8] = *(const short8*)&hB[(size_t)(bm + row) * HDIM + col + 8];
    }
    __syncthreads();

    // ---- fc1_2 + gelu + residual -> hs2 (LDS only) ----
    {
        const int bn = wave * 64;
        fx4 acc[4] = {};
        for (int kt = 0; kt < HDIM; kt += 32) {
            const short8 a = *(const short8*)&hs[l16 * LSTR + kt + quad * 8];
#pragma unroll
            for (int j = 0; j < 4; j++) {
                const short8 b = ldBf32(wf, bn + j * 16 + l16, HDIM, kt + quad * 8);
                acc[j] = MFMA(a, b, acc[j]);
            }
        }
#pragma unroll
        for (int j = 0; j < 4; j++) {
            const int n_ = bn + j * 16 + l16;
            const float bv_ = bf[n_];
#pragma unroll
            for (int r = 0; r < 4; r++) {
                const int m_ = quad * 4 + r;
                const float t = acc[j][r] + bv_;
                const float g = 0.5f * t * (1.0f + erff(t * 0.70710678118654752f));
                hs2[m_ * LSTR + n_] = f2b(b2f(hs[m_ * LSTR + n_]) + g);
            }
        }
    }
    __syncthreads();

    // ---- fea (wave w -> 16 cols) + fused head partial ----
    {
        const int bn = wave * 16;
        fx4 acc = {};
        for (int kt = 0; kt < HDIM; kt += 32) {
            const short8 a = *(const short8*)&hs2[l16 * LSTR + kt + quad * 8];
            const short8 b = ldBf32(wfe, bn + l16, HDIM, kt + quad * 8);
            acc = MFMA(a, b, acc);
        }
        const int n_ = bn + l16;
        const float bv_ = feb[n_];
        const float rwv = rw[n_];
#pragma unroll
        for (int r = 0; r < 4; r++) {
            const int m_ = quad * 4 + r;
            const float v = acc[r] + bv_;
            fea[(size_t)(bm + m_) * PDIM + n_] = v;
            float p = v * rwv;
#pragma unroll
            for (int off = 1; off < 16; off <<= 1) p += __shfl_xor(p, off);
            if (l16 == 0) part[wave][m_] = p;
        }
    }
    __syncthreads();
    if (tid < 16) {
        float s = rb[0];
#pragma unroll
        for (int w = 0; w < 8; w++) s += part[w][tid];
        out[bm + tid] = s;
    }
}

// ================= attention (unchanged — near trans-pipe floor) ============
__global__ __launch_bounds__(256) void attn_kernel(
    const u16* __restrict__ h, const u16* __restrict__ q,
    const u16* __restrict__ k, const u16* __restrict__ v,
    u16* __restrict__ hout)
{
    __shared__ __align__(16) float ks[HDIM];
    __shared__ __align__(16) float vs[HDIM];
    __shared__ float red[8];

    const int b = blockIdx.x;
    const int tid = threadIdx.x;
    const int lane = tid & 63, wave = tid >> 6;
    const int i0 = tid, i1 = tid + 256;
    const size_t base = (size_t)b * HDIM;

    const float k0 = b2f(k[base + i0]);
    const float k1 = b2f(k[base + i1]);
    ks[i0] = k0; ks[i1] = k1;
    vs[i0] = b2f(v[base + i0]);
    vs[i1] = b2f(v[base + i1]);

    float lmax = fmaxf(k0, k1), lmin = fminf(k0, k1);
#pragma unroll
    for (int off = 32; off; off >>= 1) {
        lmax = fmaxf(lmax, __shfl_xor(lmax, off));
        lmin = fminf(lmin, __shfl_xor(lmin, off));
    }
    if (lane == 0) { red[wave] = lmax; red[4 + wave] = lmin; }
    __syncthreads();
    const float kmax = fmaxf(fmaxf(red[0], red[1]), fmaxf(red[2], red[3]));
    const float kmin = fminf(fminf(red[4], red[5]), fminf(red[6], red[7]));

    float s0 = b2f(q[base + i0]);
    float s1 = b2f(q[base + i1]);
    const float mn0 = -((s0 > 0.f) ? s0 * kmax : s0 * kmin) * LOG2E;
    const float mn1 = -((s1 > 0.f) ? s1 * kmax : s1 * kmin) * LOG2E;
    s0 *= LOG2E; s1 *= LOG2E;

    const float2 s0_2  = make_float2(s0, s0),  s1_2  = make_float2(s1, s1);
    const float2 mn0_2 = make_float2(mn0, mn0), mn1_2 = make_float2(mn1, mn1);
    float2 D0 = make_float2(0.f, 0.f), N0 = D0, D1 = D0, N1 = D0;

    const float4* k4 = (const float4*)ks;
    const float4* v4 = (const float4*)vs;
#pragma unroll 4
    for (int j = 0; j < HDIM / 4; j++) {
        const float4 kk = k4[j];
        const float4 vv = v4[j];
        {
            float2 a0 = pk_fma(s0_2, make_float2(kk.x, kk.y), mn0_2);
            float2 e0; e0.x = EXP2(a0.x); e0.y = EXP2(a0.y);
            D0 = pk_add(D0, e0);
            N0 = pk_fma(e0, make_float2(vv.x, vv.y), N0);
            float2 a1 = pk_fma(s0_2, make_float2(kk.z, kk.w), mn0_2);
            float2 e1; e1.x = EXP2(a1.x); e1.y = EXP2(a1.y);
            D0 = pk_add(D0, e1);
            N0 = pk_fma(e1, make_float2(vv.z, vv.w), N0);
        }
        {
            float2 a0 = pk_fma(s1_2, make_float2(kk.x, kk.y), mn1_2);
            float2 e0; e0.x = EXP2(a0.x); e0.y = EXP2(a0.y);
            D1 = pk_add(D1, e0);
            N1 = pk_fma(e0, make_float2(vv.x, vv.y), N1);
            float2 a1 = pk_fma(s1_2, make_float2(kk.z, kk.w), mn1_2);
            float2 e1; e1.x = EXP2(a1.x); e1.y = EXP2(a1.y);
            D1 = pk_add(D1, e1);
            N1 = pk_fma(e1, make_float2(vv.z, vv.w), N1);
        }
    }
    hout[base + i0] = f2b(b2f(h[base + i0]) + (N0.x + N0.y) / (D0.x + D0.y));
    hout[base + i1] = f2b(b2f(h[base + i1]) + (N1.x + N1.y) / (D1.x + D1.y));
}

extern "C" void kernel_launch(void* const* d_in, const int* in_sizes, int n_in,
                              void* d_out, int out_size, void* d_ws, size_t ws_size,
                              hipStream_t stream) {
    const float* x      = (const float*)d_in[0];
    const float* lin0_w = (const float*)d_in[1];
    const float* lin0_b = (const float*)d_in[2];
    const float* b1_qw  = (const float*)d_in[3];
    const float* b1_qb  = (const float*)d_in[4];
    const float* b1_kw  = (const float*)d_in[5];
    const float* b1_kb  = (const float*)d_in[6];
    const float* b1_vw  = (const float*)d_in[7];
    const float* b1_vb  = (const float*)d_in[8];
    const float* b1_f1w = (const float*)d_in[9];
    const float* b1_f1b = (const float*)d_in[10];
    const float* b2_qw  = (const float*)d_in[11];
    const float* b2_qb  = (const float*)d_in[12];
    const float* b2_kw  = (const float*)d_in[13];
    const float* b2_kb  = (const float*)d_in[14];
    const float* b2_vw  = (const float*)d_in[15];
    const float* b2_vb  = (const float*)d_in[16];
    const float* b2_f1w = (const float*)d_in[17];
    const float* b2_f1b = (const float*)d_in[18];
    const float* fea_w  = (const float*)d_in[19];
    const float* fea_b  = (const float*)d_in[20];
    const float* reg_w  = (const float*)d_in[21];
    const float* reg_b  = (const float*)d_in[22];

    float* out = (float*)d_out;
    float* fea = out + BATCH;

    u16* wsb = (u16*)d_ws;
    const size_t SZ_AC = (size_t)BATCH * HDIM;
    u16* hA = wsb;
    u16* hB = hA + SZ_AC;
    u16* qb = hB + SZ_AC;
    u16* kb = qb + SZ_AC;
    u16* vb = kb + SZ_AC;

    // block 1
    fused1<<<64, 512, 0, stream>>>(x, lin0_w, lin0_b,
                                   b1_qw, b1_qb, b1_kw, b1_kb, b1_vw, b1_vb,
                                   hA, qb, kb, vb);
    attn_kernel<<<BATCH, 256, 0, stream>>>(hA, qb, kb, vb, hB);
    // block 2
    fused2<<<64, 512, 0, stream>>>(hB, b1_f1w, b1_f1b,
                                   b2_qw, b2_qb, b2_kw, b2_kb, b2_vw, b2_vb,
                                   hA, qb, kb, vb);
    attn_kernel<<<BATCH, 256, 0, stream>>>(hA, qb, kb, vb, hB);
    // heads
    fused3<<<64, 512, 0, stream>>>(hB, b2_f1w, b2_f1b, fea_w, fea_b,
                                   reg_w, reg_b, fea, out);
}

// Round 8
// 238.412 us; speedup vs baseline: 1.7795x; 1.7795x over previous
//
#include <hip/hip_runtime.h>
#include <math.h>

#define BATCH 1024
#define FIN   256
#define HDIM  512
#define PDIM  128

typedef unsigned short u16;
typedef unsigned int u32;
typedef __attribute__((ext_vector_type(8))) short short8;
typedef __attribute__((ext_vector_type(4))) float fx4;

#define LOG2E 1.4426950408889634f

__device__ __forceinline__ float b2f(u16 b) {
    return __uint_as_float(((unsigned)b) << 16);
}
__device__ __forceinline__ u16 f2b(float f) {
    unsigned u = __float_as_uint(f);
    u += 0x7fffu + ((u >> 16) & 1u);   // RNE
    return (u16)(u >> 16);
}
__device__ __forceinline__ float lo16(u32 w) { return __uint_as_float(w << 16); }
__device__ __forceinline__ float hi16(u32 w) { return __uint_as_float(w & 0xffff0000u); }

#if defined(__has_builtin)
#if __has_builtin(__builtin_amdgcn_exp2f)
#define EXP2(x) __builtin_amdgcn_exp2f(x)
#endif
#endif
#ifndef EXP2
#define EXP2(x) __expf(0.69314718055994531f * (x))
#endif

#define MFMA(a, b, c) __builtin_amdgcn_mfma_f32_16x16x32_bf16(a, b, c, 0, 0, 0)
#define LDK 72   // LDS row stride pad

// ============ dispatch 1: lin0 GEMM + weight cvt + weight transposes ========
struct CvtP {
    const float* nsrc[6]; u16* ndst[6];     // row-major bf16 (qkv weights)
    const float* tsrc[3]; u32* tdst[3];     // transposed k-pair-packed
};

__global__ __launch_bounds__(256) void lin0_cvt_kernel(
    const float* __restrict__ x, const float* __restrict__ wf,
    const float* __restrict__ bi, u16* __restrict__ oh, CvtP cp)
{
    const int tid = threadIdx.x;
    __shared__ __align__(16) u16 As[64 * LDK];
    __shared__ __align__(16) u16 Ws[64 * LDK];

    if (blockIdx.x >= 320) {
        // ---- transpose+pack: W[N][512] fp32 -> wp[256][N] u32 (k-pairs) ----
        const int id = blockIdx.x - 320;
        int wsel, tile;
        if (id < 64)       { wsel = 0; tile = id; }
        else if (id < 128) { wsel = 1; tile = id - 64; }
        else               { wsel = 2; tile = id - 128; }
        const float* W = cp.tsrc[wsel];
        u32* wp = cp.tdst[wsel];
        const int N = (wsel == 2) ? PDIM : HDIM;
        const int k0 = (tile & 7) * 64;
        const int n0 = (tile >> 3) * 64;
        u16* tt = As;   // [64 k][72 pad] u16
#pragma unroll
        for (int p = 0; p < 4; p++) {
            const int row = p * 16 + (tid >> 4);      // n_local
            const int kc = (tid & 15) * 4;            // k_local
            const float4 f = *(const float4*)&W[(size_t)(n0 + row) * HDIM + k0 + kc];
            tt[(kc + 0) * LDK + row] = f2b(f.x);
            tt[(kc + 1) * LDK + row] = f2b(f.y);
            tt[(kc + 2) * LDK + row] = f2b(f.z);
            tt[(kc + 3) * LDK + row] = f2b(f.w);
        }
        __syncthreads();
#pragma unroll
        for (int p = 0; p < 2; p++) {
            const int kkl = p * 16 + (tid >> 4);      // 0..31 (k-pair local)
            const int nc = (tid & 15) * 4;
#pragma unroll
            for (int i = 0; i < 4; i++) {
                const u32 l = tt[(2 * kkl) * LDK + nc + i];
                const u32 h = tt[(2 * kkl + 1) * LDK + nc + i];
                wp[(size_t)(k0 / 2 + kkl) * N + n0 + nc + i] = l | (h << 16);
            }
        }
        return;
    }
    if (blockIdx.x >= 128) {
        // ---- row-major bf16 cvt of 6 qkv weights ----
        const int gt = (blockIdx.x - 128) * 256 + tid;
        const int stride = 192 * 256;
        for (int t = 0; t < 6; t++) {
            const float4* s4 = (const float4*)cp.nsrc[t];
            ushort4* d4 = (ushort4*)cp.ndst[t];
            for (int i = gt; i < 65536; i += stride) {
                const float4 f = s4[i];
                ushort4 o;
                o.x = f2b(f.x); o.y = f2b(f.y); o.z = f2b(f.z); o.w = f2b(f.w);
                d4[i] = o;
            }
        }
        return;
    }
    // ---- lin0 GEMM: [1024,512] = x[1024,256] @ wf[512,256]^T + bi ----
    const int lane = tid & 63, wave = tid >> 6;
    const int wm = wave & 1, wn = wave >> 1;
    const int quad = lane >> 4, l16 = lane & 15;
    const int bn = (blockIdx.x & 7) * 64;
    const int bm = (blockIdx.x >> 3) * 64;
    const int srow = tid >> 3;
    const int scol = (tid & 7) * 8;

    const float* xb = x + (size_t)(bm + srow) * FIN + scol;
    const float* wb = wf + (size_t)(bn + srow) * FIN + scol;

    float4 fa0 = *(const float4*)xb;
    float4 fa1 = *(const float4*)(xb + 4);
    float4 fa2 = *(const float4*)(xb + (size_t)32 * FIN);
    float4 fa3 = *(const float4*)(xb + (size_t)32 * FIN + 4);
    float4 fw0 = *(const float4*)wb;
    float4 fw1 = *(const float4*)(wb + 4);
    float4 fw2 = *(const float4*)(wb + (size_t)32 * FIN);
    float4 fw3 = *(const float4*)(wb + (size_t)32 * FIN + 4);

    fx4 acc[2][2] = {};
    const int nIter = FIN / 64;    // 4
    for (int it = 0; it < nIter; ++it) {
        {
            short8 s;
            s[0] = (short)f2b(fa0.x); s[1] = (short)f2b(fa0.y);
            s[2] = (short)f2b(fa0.z); s[3] = (short)f2b(fa0.w);
            s[4] = (short)f2b(fa1.x); s[5] = (short)f2b(fa1.y);
            s[6] = (short)f2b(fa1.z); s[7] = (short)f2b(fa1.w);
            *(short8*)&As[srow * LDK + scol] = s;
            s[0] = (short)f2b(fa2.x); s[1] = (short)f2b(fa2.y);
            s[2] = (short)f2b(fa2.z); s[3] = (short)f2b(fa2.w);
            s[4] = (short)f2b(fa3.x); s[5] = (short)f2b(fa3.y);
            s[6] = (short)f2b(fa3.z); s[7] = (short)f2b(fa3.w);
            *(short8*)&As[(srow + 32) * LDK + scol] = s;
            s[0] = (short)f2b(fw0.x); s[1] = (short)f2b(fw0.y);
            s[2] = (short)f2b(fw0.z); s[3] = (short)f2b(fw0.w);
            s[4] = (short)f2b(fw1.x); s[5] = (short)f2b(fw1.y);
            s[6] = (short)f2b(fw1.z); s[7] = (short)f2b(fw1.w);
            *(short8*)&Ws[srow * LDK + scol] = s;
            s[0] = (short)f2b(fw2.x); s[1] = (short)f2b(fw2.y);
            s[2] = (short)f2b(fw2.z); s[3] = (short)f2b(fw2.w);
            s[4] = (short)f2b(fw3.x); s[5] = (short)f2b(fw3.y);
            s[6] = (short)f2b(fw3.z); s[7] = (short)f2b(fw3.w);
            *(short8*)&Ws[(srow + 32) * LDK + scol] = s;
        }
        __syncthreads();
        if (it + 1 < nIter) {
            const int kt = (it + 1) * 64;
            fa0 = *(const float4*)(xb + kt);
            fa1 = *(const float4*)(xb + kt + 4);
            fa2 = *(const float4*)(xb + (size_t)32 * FIN + kt);
            fa3 = *(const float4*)(xb + (size_t)32 * FIN + kt + 4);
            fw0 = *(const float4*)(wb + kt);
            fw1 = *(const float4*)(wb + kt + 4);
            fw2 = *(const float4*)(wb + (size_t)32 * FIN + kt);
            fw3 = *(const float4*)(wb + (size_t)32 * FIN + kt + 4);
        }
#pragma unroll
        for (int k0 = 0; k0 < 64; k0 += 32) {
            const short8 a0 = *(const short8*)&As[(wm * 32 +      l16) * LDK + k0 + quad * 8];
            const short8 a1 = *(const short8*)&As[(wm * 32 + 16 + l16) * LDK + k0 + quad * 8];
            const short8 b0 = *(const short8*)&Ws[(wn * 32 +      l16) * LDK + k0 + quad * 8];
            const short8 b1 = *(const short8*)&Ws[(wn * 32 + 16 + l16) * LDK + k0 + quad * 8];
            acc[0][0] = MFMA(a0, b0, acc[0][0]);
            acc[0][1] = MFMA(a0, b1, acc[0][1]);
            acc[1][0] = MFMA(a1, b0, acc[1][0]);
            acc[1][1] = MFMA(a1, b1, acc[1][1]);
        }
        __syncthreads();
    }
#pragma unroll
    for (int i = 0; i < 2; i++)
#pragma unroll
        for (int j = 0; j < 2; j++) {
            const int n_ = bn + wn * 32 + j * 16 + l16;
            const float bv = bi[n_];
#pragma unroll
            for (int r = 0; r < 4; r++) {
                const int m_ = bm + wm * 32 + i * 16 + quad * 4 + r;
                oh[(size_t)m_ * HDIM + n_] = f2b(acc[i][j][r] + bv);
            }
        }
}

// ============ qkv GEMM: 32x64 tiles, 3 weights, 768 blocks ==================
__global__ __launch_bounds__(256) void qkv32_kernel(
    const u16* __restrict__ A,
    const u16* __restrict__ W0, const u16* __restrict__ W1, const u16* __restrict__ W2,
    const float* __restrict__ bi0, const float* __restrict__ bi1, const float* __restrict__ bi2,
    u16* __restrict__ o0, u16* __restrict__ o1, u16* __restrict__ o2)
{
    __shared__ __align__(16) u16 As[2][32 * LDK];
    __shared__ __align__(16) u16 Ws[2][64 * LDK];

    const int tid = threadIdx.x, lane = tid & 63, wave = tid >> 6;
    const int wn = wave;
    const int quad = lane >> 4, l16 = lane & 15;
    const int which = blockIdx.x >> 3;
    const int bn = (blockIdx.x & 7) * 64;
    const int bm = blockIdx.y * 32;
    const int K = HDIM;

    const u16* W    = (which == 0) ? W0  : (which == 1) ? W1  : W2;
    const float* bi = (which == 0) ? bi0 : (which == 1) ? bi1 : bi2;
    u16* O          = (which == 0) ? o0  : (which == 1) ? o1  : o2;

    const int srow = tid >> 3;
    const int scol = (tid & 7) * 8;
    const u16* Ab = A + (size_t)(bm + srow) * K + scol;
    const u16* Wb = W + (size_t)(bn + srow) * K + scol;

    {
        *(short8*)&As[0][srow * LDK + scol]        = *(const short8*)Ab;
        *(short8*)&Ws[0][srow * LDK + scol]        = *(const short8*)Wb;
        *(short8*)&Ws[0][(srow + 32) * LDK + scol] = *(const short8*)(Wb + (size_t)32 * K);
    }

    fx4 acc[2] = {};
    const int nIter = K / 64;   // 8
    for (int it = 0; it < nIter; ++it) {
        const int cur = it & 1, nxt = cur ^ 1;
        __syncthreads();
        short8 na0, nw0, nw1;
        const bool has = (it + 1 < nIter);
        if (has) {
            const int kt = (it + 1) * 64;
            na0 = *(const short8*)(Ab + kt);
            nw0 = *(const short8*)(Wb + kt);
            nw1 = *(const short8*)(Wb + (size_t)32 * K + kt);
        }
#pragma unroll
        for (int k0 = 0; k0 < 64; k0 += 32) {
            const short8 a0 = *(const short8*)&As[cur][(     l16) * LDK + k0 + quad * 8];
            const short8 a1 = *(const short8*)&As[cur][(16 + l16) * LDK + k0 + quad * 8];
            const short8 b  = *(const short8*)&Ws[cur][(wn * 16 + l16) * LDK + k0 + quad * 8];
            acc[0] = MFMA(a0, b, acc[0]);
            acc[1] = MFMA(a1, b, acc[1]);
        }
        if (has) {
            *(short8*)&As[nxt][srow * LDK + scol] = na0;
            *(short8*)&Ws[nxt][srow * LDK + scol] = nw0;
            *(short8*)&Ws[nxt][(srow + 32) * LDK + scol] = nw1;
        }
    }

    const int n_ = bn + wn * 16 + l16;
    const float bv = bi[n_];
#pragma unroll
    for (int i = 0; i < 2; i++)
#pragma unroll
        for (int r = 0; r < 4; r++) {
            const int m_ = bm + i * 16 + quad * 4 + r;
            O[(size_t)m_ * HDIM + n_] = f2b(acc[i][r] + bv);
        }
}

// ====== attnfc: attention row + fc1 dot-products (+ optional fea/head) ======
// 1024 blocks x 512 threads; block b owns batch row b entirely. No inline asm.
template<int FEA>
__global__ __launch_bounds__(512, 4) void attnfc_kernel(
    const u16* __restrict__ h, const u16* __restrict__ q,
    const u16* __restrict__ k, const u16* __restrict__ v,
    const u32* __restrict__ wfT,          // [256][512] k-pair-packed bf16
    const float* __restrict__ bf,
    u16* __restrict__ hOut,               // FEA=0: fc1 block output
    const u32* __restrict__ wfeT,         // FEA=1: [256][128]
    const float* __restrict__ feb, const float* __restrict__ rw,
    const float* __restrict__ rb,
    float* __restrict__ fea, float* __restrict__ out)
{
    __shared__ __align__(16) float ks[HDIM];
    __shared__ __align__(16) float vs[HDIM];
    __shared__ __align__(16) float h2f[HDIM];   // bf16-rounded attn output row
    __shared__ __align__(16) float h4f[FEA ? HDIM : 1];
    __shared__ float part[FEA ? HDIM : 1];
    __shared__ float red[16];

    const int b = blockIdx.x;
    const int tid = threadIdx.x;
    const int lane = tid & 63, wave = tid >> 6;   // 8 waves
    const size_t base = (size_t)b * HDIM;

    // ---- load k,v; k max/min reduce ----
    const float kv = b2f(k[base + tid]);
    ks[tid] = kv;
    vs[tid] = b2f(v[base + tid]);
    float lmax = kv, lmin = kv;
#pragma unroll
    for (int off = 32; off; off >>= 1) {
        lmax = fmaxf(lmax, __shfl_xor(lmax, off));
        lmin = fminf(lmin, __shfl_xor(lmin, off));
    }
    if (lane == 0) { red[wave] = lmax; red[8 + wave] = lmin; }
    __syncthreads();
    float kmax = red[0], kmin = red[8];
#pragma unroll
    for (int w = 1; w < 8; w++) {
        kmax = fmaxf(kmax, red[w]);
        kmin = fminf(kmin, red[8 + w]);
    }

    // ---- attention: thread tid -> output element tid ----
    const float qv = b2f(q[base + tid]);
    const float mn = -((qv > 0.f) ? qv * kmax : qv * kmin) * LOG2E;
    const float s = qv * LOG2E;
    const float h_t = b2f(h[base + tid]);

    float D0 = 0.f, D1 = 0.f, N0 = 0.f, N1 = 0.f;
    const float4* k4 = (const float4*)ks;
    const float4* v4 = (const float4*)vs;
#pragma unroll 4
    for (int j = 0; j < HDIM / 4; j++) {
        const float4 kk = k4[j];
        const float4 vv = v4[j];
        float e;
        e = EXP2(fmaf(s, kk.x, mn)); D0 += e; N0 = fmaf(e, vv.x, N0);
        e = EXP2(fmaf(s, kk.y, mn)); D1 += e; N1 = fmaf(e, vv.y, N1);
        e = EXP2(fmaf(s, kk.z, mn)); D0 += e; N0 = fmaf(e, vv.z, N0);
        e = EXP2(fmaf(s, kk.w, mn)); D1 += e; N1 = fmaf(e, vv.w, N1);
    }
    const float hout = h_t + (N0 + N1) / (D0 + D1);
    h2f[tid] = b2f(f2b(hout));   // bf16-rounded (numeric parity with prior rounds)
    __syncthreads();

    // ---- fc1: thread n = tid computes fc1 output n over the row ----
    float a0 = 0.f, a1 = 0.f;
#pragma unroll 4
    for (int kk = 0; kk < 128; kk++) {
        const u32 w0 = wfT[(size_t)kk * HDIM + tid];
        const u32 w1 = wfT[(size_t)(kk + 128) * HDIM + tid];
        const float2 h0 = *(const float2*)&h2f[2 * kk];
        const float2 h1 = *(const float2*)&h2f[2 * (kk + 128)];
        a0 = fmaf(h0.x, lo16(w0), a0);
        a0 = fmaf(h0.y, hi16(w0), a0);
        a1 = fmaf(h1.x, lo16(w1), a1);
        a1 = fmaf(h1.y, hi16(w1), a1);
    }
    const float t = a0 + a1 + bf[tid];
    const float g = 0.5f * t * (1.0f + erff(t * 0.70710678118654752f));
    const float o2 = h2f[tid] + g;

    if (FEA == 0) {
        hOut[base + tid] = f2b(o2);
        return;
    }

    // ---- fea (128 outputs, split-K x4) + regression head ----
    h4f[tid] = b2f(f2b(o2));
    __syncthreads();
    {
        const int o = tid & 127;
        const int seg = tid >> 7;       // 0..3
        float fa = 0.f;
        const int kk0 = seg * 64;
#pragma unroll 4
        for (int kk = kk0; kk < kk0 + 64; kk++) {
            const u32 w = wfeT[(size_t)kk * PDIM + o];
            const float2 hp = *(const float2*)&h4f[2 * kk];
            fa = fmaf(hp.x, lo16(w), fa);
            fa = fmaf(hp.y, hi16(w), fa);
        }
        part[seg * PDIM + o] = fa;
    }
    __syncthreads();
    float p = 0.f;
    if (tid < PDIM) {
        const float fv = part[tid] + part[PDIM + tid] + part[2 * PDIM + tid]
                       + part[3 * PDIM + tid] + feb[tid];
        fea[(size_t)b * PDIM + tid] = fv;
        p = fv * rw[tid];
    }
#pragma unroll
    for (int off = 32; off; off >>= 1) p += __shfl_xor(p, off);
    if (lane == 0) red[wave] = p;
    __syncthreads();
    if (tid == 0) out[b] = red[0] + red[1] + rb[0];
}

extern "C" void kernel_launch(void* const* d_in, const int* in_sizes, int n_in,
                              void* d_out, int out_size, void* d_ws, size_t ws_size,
                              hipStream_t stream) {
    const float* x      = (const float*)d_in[0];
    const float* lin0_w = (const float*)d_in[1];
    const float* lin0_b = (const float*)d_in[2];
    const float* b1_qw  = (const float*)d_in[3];
    const float* b1_qb  = (const float*)d_in[4];
    const float* b1_kw  = (const float*)d_in[5];
    const float* b1_kb  = (const float*)d_in[6];
    const float* b1_vw  = (const float*)d_in[7];
    const float* b1_vb  = (const float*)d_in[8];
    const float* b1_f1w = (const float*)d_in[9];
    const float* b1_f1b = (const float*)d_in[10];
    const float* b2_qw  = (const float*)d_in[11];
    const float* b2_qb  = (const float*)d_in[12];
    const float* b2_kw  = (const float*)d_in[13];
    const float* b2_kb  = (const float*)d_in[14];
    const float* b2_vw  = (const float*)d_in[15];
    const float* b2_vb  = (const float*)d_in[16];
    const float* b2_f1w = (const float*)d_in[17];
    const float* b2_f1b = (const float*)d_in[18];
    const float* fea_w  = (const float*)d_in[19];
    const float* fea_b  = (const float*)d_in[20];
    const float* reg_w  = (const float*)d_in[21];
    const float* reg_b  = (const float*)d_in[22];

    float* out = (float*)d_out;
    float* fea = out + BATCH;

    u16* wsb = (u16*)d_ws;
    const size_t SZ_AC = (size_t)BATCH * HDIM;   // 524288 u16
    const size_t SZ_HH = (size_t)HDIM * HDIM;    // 262144 u16

    u16* hA  = wsb;
    u16* hB  = hA + SZ_AC;
    u16* qb  = hB + SZ_AC;
    u16* kb  = qb + SZ_AC;
    u16* vb  = kb + SZ_AC;
    u16* w1q = vb + SZ_AC;
    u16* w1k = w1q + SZ_HH;
    u16* w1v = w1k + SZ_HH;
    u16* w2q = w1v + SZ_HH;
    u16* w2k = w2q + SZ_HH;
    u16* w2v = w2k + SZ_HH;
    u32* wf1T = (u32*)(w2v + SZ_HH);             // [256][512] u32
    u32* wf2T = wf1T + 256 * 512;
    u32* wfeT = wf2T + 256 * 512;                // [256][128] u32

    CvtP cp;
    const float* ns[6] = {b1_qw, b1_kw, b1_vw, b2_qw, b2_kw, b2_vw};
    u16* nd[6] = {w1q, w1k, w1v, w2q, w2k, w2v};
    for (int i = 0; i < 6; i++) { cp.nsrc[i] = ns[i]; cp.ndst[i] = nd[i]; }
    cp.tsrc[0] = b1_f1w; cp.tdst[0] = wf1T;
    cp.tsrc[1] = b2_f1w; cp.tdst[1] = wf2T;
    cp.tsrc[2] = fea_w;  cp.tdst[2] = wfeT;

    // 1) lin0 (128 blk) + 6 weight cvts (192 blk) + 3 transposes (144 blk)
    lin0_cvt_kernel<<<464, 256, 0, stream>>>(x, lin0_w, lin0_b, hA, cp);

    // 2) qkv block1: 768 blocks
    qkv32_kernel<<<dim3(24, 32), 256, 0, stream>>>(hA, w1q, w1k, w1v,
                                                   b1_qb, b1_kb, b1_vb, qb, kb, vb);
    // 3) attn + fc1 block1 -> hB
    attnfc_kernel<0><<<BATCH, 512, 0, stream>>>(hA, qb, kb, vb, wf1T, b1_f1b, hB,
                                                nullptr, nullptr, nullptr, nullptr,
                                                nullptr, nullptr);
    // 4) qkv block2
    qkv32_kernel<<<dim3(24, 32), 256, 0, stream>>>(hB, w2q, w2k, w2v,
                                                   b2_qb, b2_kb, b2_vb, qb, kb, vb);
    // 5) attn + fc1 block2 + fea + head
    attnfc_kernel<1><<<BATCH, 512, 0, stream>>>(hB, qb, kb, vb, wf2T, b2_f1b, nullptr,
                                                wfeT, fea_b, reg_w, reg_b, fea, out);
}